// Round 1
// baseline (251.599 us; speedup 1.0000x reference)
//
#include <hip/hip_runtime.h>
#include <hip/hip_bf16.h>

typedef __attribute__((ext_vector_type(4))) float f32x4;
typedef __attribute__((ext_vector_type(8))) short s16x8;
typedef __attribute__((ext_vector_type(8))) unsigned short u16x8;

__device__ __forceinline__ unsigned short bfbits(float f) {
  unsigned int u = __builtin_bit_cast(unsigned int, f);
  return (unsigned short)((u + 0x8000u) >> 16);   // round-half-up to bf16
}
__device__ __forceinline__ float bf2f(unsigned short b) {
  return __builtin_bit_cast(float, ((unsigned int)b) << 16);
}

__device__ __forceinline__ void gll16(void* lds, const void* g) {
  __builtin_amdgcn_global_load_lds(
      (const __attribute__((address_space(1))) unsigned int*)g,
      (__attribute__((address_space(3))) unsigned int*)lds, 16, 0, 0);
}

// ---------------------------------------------------------------------------
// Prep: convW_1 [3,3,256,512] f32 -> bf16 tiles in the exact LDS image layout
// for each (K-step t = kpos*8 + c/32, n-block nb): [cq=cl/8][nl][ce=cl%8]
// Wt index = (t*4 + nb)*4096 + cq*1024 + nl*8 + ce
// ---------------------------------------------------------------------------
__global__ void prep_weights(const float* __restrict__ w,
                             __hip_bfloat16* __restrict__ wt) {
  int u = blockIdx.x * 256 + threadIdx.x;   // 9*32*512 = 147456 threads
  int n = u & 511;
  int c8 = (u >> 9) & 31;
  int kpos = u >> 14;
  int t = kpos * 8 + (c8 >> 2);
  int cq = c8 & 3;
  const float* src = w + ((kpos * 256 + c8 * 8) * 512) + n;
  u16x8 d;
#pragma unroll
  for (int j = 0; j < 8; ++j) d[j] = bfbits(src[j * 512]);
  int nb = n >> 7, nl = n & 127;
  *reinterpret_cast<u16x8*>(wt + ((t * 4 + nb) * 4096 + cq * 1024 + nl * 8)) = d;
}

// ---------------------------------------------------------------------------
// Fused conv(implicit GEMM, bf16 MFMA) + bias1 + relu + capsule matmul + bias2
// M = 25088 pixels, N = 512 couts, K = 2304.  BM=128 BN=128 BK=32, 4 waves.
// ---------------------------------------------------------------------------
__global__ __launch_bounds__(256, 3)
void caps_main(const float* __restrict__ in, const __hip_bfloat16* __restrict__ wt,
               const float* __restrict__ bias1, const float* __restrict__ capsW,
               const float* __restrict__ capsB, float* __restrict__ out) {
  __shared__ __align__(16) unsigned char smem[32768];
  __hip_bfloat16* sA = (__hip_bfloat16*)smem;            // [4][128][8] 8KB
  __hip_bfloat16* sB = (__hip_bfloat16*)(smem + 8192);   // [4][128][8] 8KB

  int bid = (int)blockIdx.x;
  bid = (bid & 7) * 98 + (bid >> 3);   // XCD-chunked swizzle (784 = 8*98)
  int mblk = bid >> 2;
  int nb = bid & 3;
  int p0 = mblk * 128;

  int tid = threadIdx.x;
  int lane = tid & 63;
  int wv = tid >> 6;
  int wm = (wv >> 1) * 64;
  int wn = (wv & 1) * 64;
  int col = lane & 15;
  int lq = lane >> 4;

  // A-staging role: thread -> (m row, c half)
  int am = tid & 127;
  int ah = tid >> 7;
  int p = p0 + am;
  int bb = p / 784;
  int rr = p - bb * 784;
  int ho = rr / 28;
  int wo = rr - ho * 28;

  f32x4 acc[4][4] = {};

  const __hip_bfloat16* wtb = wt + nb * 4096;

  for (int kp = 0; kp < 9; ++kp) {
    int kh = kp / 3;
    int kw = kp - kh * 3;
    int h = 2 * ho + kh, ww = 2 * wo + kw;       // SAME pad_lo = 0
    bool valid = (h < 56) && (ww < 56);
    const float* arow = in + (((bb * 56 + h) * 56 + ww) * 256) + ah * 16;
#pragma unroll
    for (int tc = 0; tc < 8; ++tc) {
      int t = kp * 8 + tc;
      __syncthreads();
      // ---- stage B (async global->LDS, pre-tiled bf16) ----
      const __hip_bfloat16* bsrc = wtb + t * 16384 + tid * 8;
      gll16(sB + (wv * 512), bsrc);
      gll16(sB + 2048 + (wv * 512), bsrc + 2048);
      // ---- stage A (f32 load -> bf16 -> LDS [cq][m][8]) ----
      f32x4 v0, v1, v2, v3;
      if (valid) {
        const f32x4* apv = (const f32x4*)(arow + tc * 32);
        v0 = apv[0]; v1 = apv[1]; v2 = apv[2]; v3 = apv[3];
      } else {
        v0 = f32x4{0.f, 0.f, 0.f, 0.f}; v1 = v0; v2 = v0; v3 = v0;
      }
      u16x8 pk0, pk1;
#pragma unroll
      for (int j = 0; j < 4; ++j) {
        pk0[j] = bfbits(v0[j]); pk0[j + 4] = bfbits(v1[j]);
        pk1[j] = bfbits(v2[j]); pk1[j + 4] = bfbits(v3[j]);
      }
      *(u16x8*)(sA + (ah * 2) * 1024 + am * 8) = pk0;
      *(u16x8*)(sA + (ah * 2 + 1) * 1024 + am * 8) = pk1;
      __syncthreads();
      // ---- compute: 16 MFMA per wave ----
      s16x8 af[4], bfr[4];
#pragma unroll
      for (int mf = 0; mf < 4; ++mf)
        af[mf] = *(const s16x8*)(sA + lq * 1024 + (wm + 16 * mf + col) * 8);
#pragma unroll
      for (int nf = 0; nf < 4; ++nf)
        bfr[nf] = *(const s16x8*)(sB + lq * 1024 + (wn + 16 * nf + col) * 8);
#pragma unroll
      for (int mf = 0; mf < 4; ++mf)
#pragma unroll
        for (int nf = 0; nf < 4; ++nf)
          acc[mf][nf] = __builtin_amdgcn_mfma_f32_16x16x32_bf16(
              af[mf], bfr[nf], acc[mf][nf], 0, 0, 0);
    }
  }

  __syncthreads();   // staging LDS is about to be reused as per-wave y tiles

  // ---- epilogue: y = relu(acc + bias1) -> per-wave swizzled LDS (bf16) ----
  __hip_bfloat16* yw = (__hip_bfloat16*)smem + wv * 4096;   // 64x64, 8KB
  int nBase = nb * 128 + wn;
#pragma unroll
  for (int nf = 0; nf < 4; ++nf) {
    float b1v = bias1[nBase + nf * 16 + col];
#pragma unroll
    for (int mf = 0; mf < 4; ++mf) {
      f32x4 a = acc[mf][nf];
#pragma unroll
      for (int r = 0; r < 4; ++r) {
        int pl = mf * 16 + lq * 4 + r;
        int nl = nf * 16 + col;
        float v = a[r] + b1v;
        v = v > 0.f ? v : 0.f;
        int off = (pl * 128 + nl * 2) ^ ((pl & 7) << 4);
        *(unsigned short*)((char*)yw + off) = bfbits(v);
      }
    }
  }
  __asm__ volatile("s_waitcnt lgkmcnt(0)" ::: "memory");

  // ---- capsule 16x16 matmul per group via MFMA (K=16, zero-padded) ----
  int gb = nb * 8 + (wv & 1) * 4;   // wave's 4 consecutive global groups
  s16x8 wf[4];
  f32x4 cinit[4];
#pragma unroll
  for (int g = 0; g < 4; ++g) {
    int gg = gb + g;
    s16x8 bw = {0, 0, 0, 0, 0, 0, 0, 0};
    if (lq < 2) {
#pragma unroll
      for (int j = 0; j < 8; ++j)
        bw[j] = (short)bfbits(capsW[(8 * lq + j) * 512 + gg * 16 + col]);
    }
    wf[g] = bw;
    float cb = capsB[gg * 16 + col];
    cinit[g] = f32x4{cb, cb, cb, cb};
  }
#pragma unroll
  for (int g = 0; g < 4; ++g) {
#pragma unroll
    for (int mf = 0; mf < 4; ++mf) {
      int prow = 16 * mf + col;
      s16x8 af = {0, 0, 0, 0, 0, 0, 0, 0};
      if (lq < 2) {
        int off = (prow * 128 + g * 32 + lq * 16) ^ ((prow & 7) << 4);
        af = *(const s16x8*)((char*)yw + off);
      }
      f32x4 dd = __builtin_amdgcn_mfma_f32_16x16x32_bf16(af, wf[g], cinit[g], 0, 0, 0);
      long pgl = (long)(p0 + wm) + 16 * mf;
#pragma unroll
      for (int r = 0; r < 4; ++r) {
        long pg = pgl + 4 * lq + r;
        out[(pg * 16 + col) * 32 + gb + g] = dd[r];
      }
    }
  }
}

extern "C" void kernel_launch(void* const* d_in, const int* in_sizes, int n_in,
                              void* d_out, int out_size, void* d_ws, size_t ws_size,
                              hipStream_t stream) {
  const float* inputs = (const float*)d_in[0];
  const float* convW  = (const float*)d_in[1];
  const float* bias1  = (const float*)d_in[2];
  const float* capsW  = (const float*)d_in[3];
  const float* capsB  = (const float*)d_in[4];
  float* out = (float*)d_out;
  __hip_bfloat16* wt = (__hip_bfloat16*)d_ws;   // 2.25 MB

  prep_weights<<<576, 256, 0, stream>>>(convW, wt);
  caps_main<<<784, 256, 0, stream>>>(inputs, wt, bias1, capsW, capsB, out);
}

// Round 2
// 145.215 us; speedup vs baseline: 1.7326x; 1.7326x over previous
//
#include <hip/hip_runtime.h>
#include <hip/hip_bf16.h>

typedef __attribute__((ext_vector_type(4))) float f32x4;
typedef __attribute__((ext_vector_type(8))) short s16x8;
typedef __attribute__((ext_vector_type(8))) unsigned short u16x8;

__device__ __forceinline__ unsigned short bfbits(float f) {
  unsigned int u = __builtin_bit_cast(unsigned int, f);
  return (unsigned short)((u + 0x8000u) >> 16);   // round-half-up to bf16
}

__device__ __forceinline__ void gll16(void* lds, const void* g) {
  __builtin_amdgcn_global_load_lds(
      (const __attribute__((address_space(1))) unsigned int*)g,
      (__attribute__((address_space(3))) unsigned int*)lds, 16, 0, 0);
}

// ---------------------------------------------------------------------------
// Prep 1: convW_1 [3,3,256,512] f32 -> bf16 tiles in LDS image layout.
// For K-step t = kpos*8 + c/32, n-block nb: [cq=cl/8][nl][ce=cl%8]
// Wt index = (t*4 + nb)*4096 + cq*1024 + nl*8 + ce
// ---------------------------------------------------------------------------
__global__ void prep_weights(const float* __restrict__ w,
                             __hip_bfloat16* __restrict__ wt) {
  int u = blockIdx.x * 256 + threadIdx.x;   // 9*32*512 = 147456 threads
  int n = u & 511;
  int c8 = (u >> 9) & 31;
  int kpos = u >> 14;
  int t = kpos * 8 + (c8 >> 2);
  int cq = c8 & 3;
  const float* src = w + ((kpos * 256 + c8 * 8) * 512) + n;
  u16x8 d;
#pragma unroll
  for (int j = 0; j < 8; ++j) d[j] = bfbits(src[j * 512]);
  int nb = n >> 7, nl = n & 127;
  *reinterpret_cast<u16x8*>(wt + ((t * 4 + nb) * 4096 + cq * 1024 + nl * 8)) = d;
}

// ---------------------------------------------------------------------------
// Prep 2: input [32,56,56,256] f32 -> bf16 zero-padded [32,57,57,256]
// ---------------------------------------------------------------------------
__global__ void prep_input(const float* __restrict__ in,
                           __hip_bfloat16* __restrict__ dst) {
  int u = blockIdx.x * 256 + threadIdx.x;   // 32*57*57*32 = 3326976 chunks of 8
  int c8 = u & 31;
  int q = u >> 5;                 // (b*57+h)*57 + w
  int w = q % 57;
  int q2 = q / 57;                // b*57 + h
  int h = q2 % 57;
  int b = q2 / 57;
  u16x8 d = {0, 0, 0, 0, 0, 0, 0, 0};
  if (h < 56 && w < 56) {
    const float* src = in + (((b * 56 + h) * 56 + w) * 256) + c8 * 8;
    f32x4 v0 = *(const f32x4*)src;
    f32x4 v1 = *(const f32x4*)(src + 4);
#pragma unroll
    for (int j = 0; j < 4; ++j) { d[j] = bfbits(v0[j]); d[j + 4] = bfbits(v1[j]); }
  }
  *reinterpret_cast<u16x8*>(dst + (long)u * 8) = d;
}

// ---------------------------------------------------------------------------
// Main (fast path): implicit-GEMM conv via bf16 MFMA, depth-2 prefetch
// pipeline (3 LDS buffers, counted vmcnt, raw s_barrier), fused epilogue.
// M=25088, N=512, K=2304. BM=128 BN=128 BK=32, 4 waves.
// ---------------------------------------------------------------------------
__global__ __launch_bounds__(256, 3)
void caps_main_fast(const __hip_bfloat16* __restrict__ inp,   // padded bf16
                    const __hip_bfloat16* __restrict__ wt,
                    const float* __restrict__ bias1,
                    const float* __restrict__ capsW,
                    const float* __restrict__ capsB,
                    float* __restrict__ out) {
  __shared__ __align__(16) unsigned char smem[49152];   // A: 3x8KB, B: 3x8KB

  int bid = (int)blockIdx.x;
  bid = (bid & 7) * 98 + (bid >> 3);   // XCD-chunked swizzle (784 = 8*98)
  int mblk = bid >> 2;
  int nb = bid & 3;
  int p0 = mblk * 128;

  int tid = threadIdx.x;
  int lane = tid & 63;
  int wv = tid >> 6;
  int wm = (wv >> 1) * 64;
  int wn = (wv & 1) * 64;
  int col = lane & 15;
  int lq = lane >> 4;

  // staging role: thread -> (m row, cq half)
  int m = tid & 127;
  int half = tid >> 7;
  int p = p0 + m;
  int bb = p / 784;
  int rr = p - bb * 784;
  int ho = rr / 28;
  int wo = rr - ho * 28;
  const __hip_bfloat16* pixbase = inp + ((bb * 57 + 2 * ho) * 57 + 2 * wo) * 256;
  const __hip_bfloat16* wtb = wt + nb * 4096;

  f32x4 acc[4][4] = {};

  auto stage = [&](int buf, int t) {
    int kp = t >> 3, tc = t & 7;
    int kh = kp / 3, kw = kp - kh * 3;
    const __hip_bfloat16* arow = pixbase + (kh * 57 + kw) * 256 + tc * 32;
    __hip_bfloat16* sa = (__hip_bfloat16*)smem + buf * 4096;
    __hip_bfloat16* sb = (__hip_bfloat16*)(smem + 24576) + buf * 4096;
    // B tile (pre-tiled bf16, linear)
    const __hip_bfloat16* bsrc = wtb + t * 16384 + tid * 8;
    gll16(sb + wv * 512, bsrc);
    gll16(sb + 2048 + wv * 512, bsrc + 2048);
    // A tile: [cq][m][8], cq = i*2 + half
    gll16(sa + wv * 512, arow + half * 8);
    gll16(sa + 2048 + wv * 512, arow + (2 + half) * 8);
  };

  // prologue: 2 tiles in flight
  stage(0, 0);
  stage(1, 1);
  __asm__ volatile("s_waitcnt vmcnt(4)" ::: "memory");   // tile 0 landed
  __builtin_amdgcn_s_barrier();

  int rd = 0;
  for (int t = 0; t < 72; ++t) {
    const __hip_bfloat16* sa = (const __hip_bfloat16*)smem + rd * 4096;
    const __hip_bfloat16* sb = (const __hip_bfloat16*)(smem + 24576) + rd * 4096;
    // frag reads from current buffer
    s16x8 af[4], bfr[4];
#pragma unroll
    for (int mf = 0; mf < 4; ++mf)
      af[mf] = *(const s16x8*)(sa + lq * 1024 + (wm + 16 * mf + col) * 8);
#pragma unroll
    for (int nf = 0; nf < 4; ++nf)
      bfr[nf] = *(const s16x8*)(sb + lq * 1024 + (wn + 16 * nf + col) * 8);
    // prefetch t+2 into the third buffer
    if (t + 2 < 72) {
      int st = rd + 2; if (st >= 3) st -= 3;
      stage(st, t + 2);
    }
#pragma unroll
    for (int mf = 0; mf < 4; ++mf)
#pragma unroll
      for (int nf = 0; nf < 4; ++nf)
        acc[mf][nf] = __builtin_amdgcn_mfma_f32_16x16x32_bf16(
            af[mf], bfr[nf], acc[mf][nf], 0, 0, 0);
    // ensure tile t+1 (oldest outstanding stage) has landed; keep t+2 in flight
    if (t < 69) {
      __asm__ volatile("s_waitcnt vmcnt(4)" ::: "memory");
    } else {
      __asm__ volatile("s_waitcnt vmcnt(0)" ::: "memory");
    }
    __builtin_amdgcn_s_barrier();
    rd = (rd + 1 == 3) ? 0 : rd + 1;
  }

  // ---- epilogue: y = relu(acc + bias1) -> per-wave swizzled LDS (bf16) ----
  __hip_bfloat16* yw = (__hip_bfloat16*)smem + wv * 4096;   // 64x64 per wave
  int nBase = nb * 128 + wn;
#pragma unroll
  for (int nf = 0; nf < 4; ++nf) {
    float b1v = bias1[nBase + nf * 16 + col];
#pragma unroll
    for (int mf = 0; mf < 4; ++mf) {
      f32x4 a = acc[mf][nf];
#pragma unroll
      for (int r = 0; r < 4; ++r) {
        int pl = mf * 16 + lq * 4 + r;
        int nl = nf * 16 + col;
        float v = a[r] + b1v;
        v = v > 0.f ? v : 0.f;
        int off = (pl * 128 + nl * 2) ^ ((pl & 7) << 4);
        *(unsigned short*)((char*)yw + off) = bfbits(v);
      }
    }
  }

  // ---- capsule 16x16 matmul per group via MFMA (K=16 zero-padded) ----
  int gb = nb * 8 + (wv & 1) * 4;   // wave's 4 consecutive global groups
  s16x8 wf[4];
  f32x4 cinit[4];
#pragma unroll
  for (int g = 0; g < 4; ++g) {
    int gg = gb + g;
    s16x8 bw = {0, 0, 0, 0, 0, 0, 0, 0};
    if (lq < 2) {
#pragma unroll
      for (int j = 0; j < 8; ++j)
        bw[j] = (short)bfbits(capsW[(8 * lq + j) * 512 + gg * 16 + col]);
    }
    wf[g] = bw;
    float cb = capsB[gg * 16 + col];
    cinit[g] = f32x4{cb, cb, cb, cb};
  }
#pragma unroll
  for (int mf = 0; mf < 4; ++mf) {
    int prow = 16 * mf + col;
    f32x4 dd[4];
#pragma unroll
    for (int g = 0; g < 4; ++g) {
      s16x8 afv = {0, 0, 0, 0, 0, 0, 0, 0};
      if (lq < 2) {
        int off = (prow * 128 + g * 32 + lq * 16) ^ ((prow & 7) << 4);
        afv = *(const s16x8*)((char*)yw + off);
      }
      dd[g] = __builtin_amdgcn_mfma_f32_16x16x32_bf16(afv, wf[g], cinit[g], 0, 0, 0);
    }
    long pgl = (long)(p0 + wm) + 16 * mf;
#pragma unroll
    for (int r = 0; r < 4; ++r) {
      long pg = pgl + 4 * lq + r;
      f32x4 o = {dd[0][r], dd[1][r], dd[2][r], dd[3][r]};
      *(f32x4*)(out + (pg * 16 + col) * 32 + gb) = o;
    }
  }
}

// ---------------------------------------------------------------------------
// Fallback main (round-1 kernel, only needs 2.3 MB ws) in case ws is small
// ---------------------------------------------------------------------------
__global__ __launch_bounds__(256, 3)
void caps_main_v1(const float* __restrict__ in, const __hip_bfloat16* __restrict__ wt,
                  const float* __restrict__ bias1, const float* __restrict__ capsW,
                  const float* __restrict__ capsB, float* __restrict__ out) {
  __shared__ __align__(16) unsigned char smem[32768];
  __hip_bfloat16* sA = (__hip_bfloat16*)smem;
  __hip_bfloat16* sB = (__hip_bfloat16*)(smem + 8192);

  int bid = (int)blockIdx.x;
  bid = (bid & 7) * 98 + (bid >> 3);
  int mblk = bid >> 2;
  int nb = bid & 3;
  int p0 = mblk * 128;

  int tid = threadIdx.x;
  int lane = tid & 63;
  int wv = tid >> 6;
  int wm = (wv >> 1) * 64;
  int wn = (wv & 1) * 64;
  int col = lane & 15;
  int lq = lane >> 4;

  int am = tid & 127;
  int ah = tid >> 7;
  int p = p0 + am;
  int bb = p / 784;
  int rr = p - bb * 784;
  int ho = rr / 28;
  int wo = rr - ho * 28;

  f32x4 acc[4][4] = {};
  const __hip_bfloat16* wtb = wt + nb * 4096;

  for (int kp = 0; kp < 9; ++kp) {
    int kh = kp / 3;
    int kw = kp - kh * 3;
    int h = 2 * ho + kh, ww = 2 * wo + kw;
    bool valid = (h < 56) && (ww < 56);
    const float* arow = in + (((bb * 56 + h) * 56 + ww) * 256) + ah * 16;
#pragma unroll
    for (int tc = 0; tc < 8; ++tc) {
      int t = kp * 8 + tc;
      __syncthreads();
      const __hip_bfloat16* bsrc = wtb + t * 16384 + tid * 8;
      gll16(sB + (wv * 512), bsrc);
      gll16(sB + 2048 + (wv * 512), bsrc + 2048);
      f32x4 v0, v1, v2, v3;
      if (valid) {
        const f32x4* apv = (const f32x4*)(arow + tc * 32);
        v0 = apv[0]; v1 = apv[1]; v2 = apv[2]; v3 = apv[3];
      } else {
        v0 = f32x4{0.f, 0.f, 0.f, 0.f}; v1 = v0; v2 = v0; v3 = v0;
      }
      u16x8 pk0, pk1;
#pragma unroll
      for (int j = 0; j < 4; ++j) {
        pk0[j] = bfbits(v0[j]); pk0[j + 4] = bfbits(v1[j]);
        pk1[j] = bfbits(v2[j]); pk1[j + 4] = bfbits(v3[j]);
      }
      *(u16x8*)(sA + (ah * 2) * 1024 + am * 8) = pk0;
      *(u16x8*)(sA + (ah * 2 + 1) * 1024 + am * 8) = pk1;
      __syncthreads();
      s16x8 af[4], bfr[4];
#pragma unroll
      for (int mf = 0; mf < 4; ++mf)
        af[mf] = *(const s16x8*)(sA + lq * 1024 + (wm + 16 * mf + col) * 8);
#pragma unroll
      for (int nf = 0; nf < 4; ++nf)
        bfr[nf] = *(const s16x8*)(sB + lq * 1024 + (wn + 16 * nf + col) * 8);
#pragma unroll
      for (int mf = 0; mf < 4; ++mf)
#pragma unroll
        for (int nf = 0; nf < 4; ++nf)
          acc[mf][nf] = __builtin_amdgcn_mfma_f32_16x16x32_bf16(
              af[mf], bfr[nf], acc[mf][nf], 0, 0, 0);
    }
  }

  __syncthreads();

  __hip_bfloat16* yw = (__hip_bfloat16*)smem + wv * 4096;
  int nBase = nb * 128 + wn;
#pragma unroll
  for (int nf = 0; nf < 4; ++nf) {
    float b1v = bias1[nBase + nf * 16 + col];
#pragma unroll
    for (int mf = 0; mf < 4; ++mf) {
      f32x4 a = acc[mf][nf];
#pragma unroll
      for (int r = 0; r < 4; ++r) {
        int pl = mf * 16 + lq * 4 + r;
        int nl = nf * 16 + col;
        float v = a[r] + b1v;
        v = v > 0.f ? v : 0.f;
        int off = (pl * 128 + nl * 2) ^ ((pl & 7) << 4);
        *(unsigned short*)((char*)yw + off) = bfbits(v);
      }
    }
  }

  int gb = nb * 8 + (wv & 1) * 4;
  s16x8 wf[4];
  f32x4 cinit[4];
#pragma unroll
  for (int g = 0; g < 4; ++g) {
    int gg = gb + g;
    s16x8 bw = {0, 0, 0, 0, 0, 0, 0, 0};
    if (lq < 2) {
#pragma unroll
      for (int j = 0; j < 8; ++j)
        bw[j] = (short)bfbits(capsW[(8 * lq + j) * 512 + gg * 16 + col]);
    }
    wf[g] = bw;
    float cb = capsB[gg * 16 + col];
    cinit[g] = f32x4{cb, cb, cb, cb};
  }
#pragma unroll
  for (int mf = 0; mf < 4; ++mf) {
    int prow = 16 * mf + col;
    f32x4 dd[4];
#pragma unroll
    for (int g = 0; g < 4; ++g) {
      s16x8 afv = {0, 0, 0, 0, 0, 0, 0, 0};
      if (lq < 2) {
        int off = (prow * 128 + g * 32 + lq * 16) ^ ((prow & 7) << 4);
        afv = *(const s16x8*)((char*)yw + off);
      }
      dd[g] = __builtin_amdgcn_mfma_f32_16x16x32_bf16(afv, wf[g], cinit[g], 0, 0, 0);
    }
    long pgl = (long)(p0 + wm) + 16 * mf;
#pragma unroll
    for (int r = 0; r < 4; ++r) {
      long pg = pgl + 4 * lq + r;
      f32x4 o = {dd[0][r], dd[1][r], dd[2][r], dd[3][r]};
      *(f32x4*)(out + (pg * 16 + col) * 32 + gb) = o;
    }
  }
}

extern "C" void kernel_launch(void* const* d_in, const int* in_sizes, int n_in,
                              void* d_out, int out_size, void* d_ws, size_t ws_size,
                              hipStream_t stream) {
  const float* inputs = (const float*)d_in[0];
  const float* convW  = (const float*)d_in[1];
  const float* bias1  = (const float*)d_in[2];
  const float* capsW  = (const float*)d_in[3];
  const float* capsB  = (const float*)d_in[4];
  float* out = (float*)d_out;

  __hip_bfloat16* wt = (__hip_bfloat16*)d_ws;                       // 2.36 MB
  const size_t IN_OFF = 4u << 20;                                   // 4 MB
  const size_t NEED = IN_OFF + (size_t)32 * 57 * 57 * 256 * 2;      // 57.4 MB

  prep_weights<<<576, 256, 0, stream>>>(convW, wt);
  if (ws_size >= NEED) {
    __hip_bfloat16* inp = (__hip_bfloat16*)((char*)d_ws + IN_OFF);
    prep_input<<<12996, 256, 0, stream>>>(inputs, inp);
    caps_main_fast<<<784, 256, 0, stream>>>(inp, wt, bias1, capsW, capsB, out);
  } else {
    caps_main_v1<<<784, 256, 0, stream>>>(inputs, wt, bias1, capsW, capsB, out);
  }
}

// Round 3
// 109.701 us; speedup vs baseline: 2.2935x; 1.3237x over previous
//
#include <hip/hip_runtime.h>
#include <hip/hip_bf16.h>

typedef __attribute__((ext_vector_type(4))) float f32x4;
typedef __attribute__((ext_vector_type(8))) short s16x8;
typedef __attribute__((ext_vector_type(8))) unsigned short u16x8;
typedef __attribute__((ext_vector_type(4))) unsigned short u16x4;

__device__ __forceinline__ unsigned short bfbits(float f) {
  unsigned int u = __builtin_bit_cast(unsigned int, f);
  return (unsigned short)((u + 0x8000u) >> 16);   // round-half-up to bf16
}

__device__ __forceinline__ void gll16(void* lds, const void* g) {
  __builtin_amdgcn_global_load_lds(
      (const __attribute__((address_space(1))) unsigned int*)g,
      (__attribute__((address_space(3))) unsigned int*)lds, 16, 0, 0);
}

// ---------------------------------------------------------------------------
// Prep 1: convW_1 [3,3,256,512] f32 -> bf16 tiles in LDS image layout.
// For K-step t = kpos*8 + c/32, n-block nb: [cq=cl/8][nl][ce=cl%8]
// Wt index = (t*4 + nb)*4096 + cq*1024 + nl*8 + ce
// ---------------------------------------------------------------------------
__global__ void prep_weights(const float* __restrict__ w,
                             __hip_bfloat16* __restrict__ wt) {
  int u = blockIdx.x * 256 + threadIdx.x;   // 147456 threads
  int n = u & 511;
  int c8 = (u >> 9) & 31;
  int kpos = u >> 14;
  int t = kpos * 8 + (c8 >> 2);
  int cq = c8 & 3;
  const float* src = w + ((kpos * 256 + c8 * 8) * 512) + n;
  u16x8 d;
#pragma unroll
  for (int j = 0; j < 8; ++j) d[j] = bfbits(src[j * 512]);
  int nb = n >> 7, nl = n & 127;
  *reinterpret_cast<u16x8*>(wt + ((t * 4 + nb) * 4096 + cq * 1024 + nl * 8)) = d;
}

// ---------------------------------------------------------------------------
// Prep 2: input [32,56,56,256] f32 -> bf16 transposed-padded layout
//   [b][h 0..56][par][cq 0..31][wp 0..28][8]
// element strides: wp:8  cq:232  par:7424  h:14848  b:846336
// Row h=56 and wp=28 (w=56/57) are zero padding.
// One block per (b,h): coalesced read, LDS transpose, coalesced write.
// ---------------------------------------------------------------------------
__global__ __launch_bounds__(256)
void prep_input_t(const float* __restrict__ in, __hip_bfloat16* __restrict__ dst) {
  __shared__ __align__(16) unsigned short row[14848];
  int bh = blockIdx.x;            // 32*57 = 1824
  int h = bh % 57, b = bh / 57;
  int t = threadIdx.x;
  __hip_bfloat16* d = (__hip_bfloat16*)dst + (long)bh * 14848;
  if (h < 56) {
    if (t < 64) {   // zero the wp=28 pad slots
      int par = t >> 5, cq = t & 31;
      u16x4 z = {0, 0, 0, 0};
      *(u16x4*)(row + (par * 32 + cq) * 232 + 224) = z;
      *(u16x4*)(row + (par * 32 + cq) * 232 + 228) = z;
    }
    const float* src = in + (long)(b * 56 + h) * 56 * 256;
#pragma unroll
    for (int j = 0; j < 14; ++j) {
      int idx = j * 256 + t;       // f32x4 index in row, 3584 total
      f32x4 v = *(const f32x4*)(src + idx * 4);
      int e0 = idx * 4;
      int w = e0 >> 8, c = e0 & 255;
      int off = ((w & 1) * 32 + (c >> 3)) * 232 + (w >> 1) * 8 + (c & 7);
      u16x4 q = {bfbits(v[0]), bfbits(v[1]), bfbits(v[2]), bfbits(v[3])};
      *(u16x4*)(row + off) = q;
    }
    __syncthreads();
    for (int i = t; i < 1856; i += 256)
      *(u16x8*)(d + i * 8) = *(const u16x8*)(row + i * 8);
  } else {
    u16x8 z = {0, 0, 0, 0, 0, 0, 0, 0};
    for (int i = t; i < 1856; i += 256) *(u16x8*)(d + i * 8) = z;
  }
}

// ---------------------------------------------------------------------------
// Main: implicit-GEMM conv, BM=256 BN=128 BK=32, 512 threads (8 waves,
// wave tile 64x64), depth-2 prefetch over 3 LDS buffers, counted vmcnt,
// fully coalesced A/B staging via global_load_lds, fused capsule epilogue.
// ---------------------------------------------------------------------------
__global__ __launch_bounds__(512, 4)
void caps_main_fast(const __hip_bfloat16* __restrict__ inp,   // transposed bf16
                    const __hip_bfloat16* __restrict__ wt,
                    const float* __restrict__ bias1,
                    const float* __restrict__ capsW,
                    const float* __restrict__ capsB,
                    float* __restrict__ out) {
  __shared__ __align__(16) unsigned char smem[73728];   // 3 x (A 16KB + B 8KB)

  int bid = (int)blockIdx.x;
  bid = (bid & 7) * 49 + (bid >> 3);   // XCD swizzle (392 = 8*49)
  int mblk = bid >> 2;                 // 0..97
  int nb = bid & 3;
  int p0 = mblk * 256;

  int tid = threadIdx.x;
  int lane = tid & 63;
  int wv = tid >> 6;                   // 0..7
  int wm = (wv >> 1) * 64;             // m offset in 256
  int wn = (wv & 1) * 64;              // n offset in 128
  int col = lane & 15;
  int lq = lane >> 4;

  // staging roles
  int mq = wv >> 1;                    // A m-quad (== wm/64)
  int cqa = (wv & 1) * 2;              // A cq base {0,2}
  int bcq = wv >> 1;                   // B cq 0..3
  int bnh = wv & 1;                    // B n-half

  // per-thread pixel (fixed): p = p0 + mq*64 + lane
  int p = p0 + mq * 64 + lane;
  int b = p / 784;
  int rr = p - b * 784;
  int ho = rr / 28;
  int wo = rr - ho * 28;
  int base0 = b * 846336 + 2 * ho * 14848 + wo * 8;   // + kh*14848 + par*7424 + (kw>>1)*8 + cq*232

  const __hip_bfloat16* wtb = wt + nb * 4096;

  f32x4 acc[4][4] = {};

  auto stage = [&](int buf, int t) {
    int kp = t >> 3, tc = t & 7;
    int kh = (kp * 11) >> 5;           // kp/3 for kp in 0..8
    int kw = kp - kh * 3;
    __hip_bfloat16* sa = (__hip_bfloat16*)smem + buf * 12288;
    __hip_bfloat16* sb = sa + 8192;
    const __hip_bfloat16* as =
        inp + base0 + kh * 14848 + (kw & 1) * 7424 + (kw >> 1) * 8 + (tc * 4 + cqa) * 232;
    gll16(sa + cqa * 2048 + mq * 512, as);            // lane stride 16B: coalesced
    gll16(sa + (cqa + 1) * 2048 + mq * 512, as + 232);
    const __hip_bfloat16* bs = wtb + t * 16384 + bcq * 1024 + bnh * 512 + lane * 8;
    gll16(sb + bcq * 1024 + bnh * 512, bs);
  };

  // prologue: 2 tiles in flight (3 loads/wave each)
  stage(0, 0);
  stage(1, 1);
  __asm__ volatile("s_waitcnt vmcnt(3)" ::: "memory");   // tile 0 landed
  __builtin_amdgcn_s_barrier();

  int rd = 0;
  for (int t = 0; t < 72; ++t) {
    const __hip_bfloat16* sa = (const __hip_bfloat16*)smem + rd * 12288;
    const __hip_bfloat16* sb = sa + 8192;
    s16x8 af[4], bfr[4];
#pragma unroll
    for (int mf = 0; mf < 4; ++mf)
      af[mf] = *(const s16x8*)(sa + lq * 2048 + (wm + 16 * mf + col) * 8);
#pragma unroll
    for (int nf = 0; nf < 4; ++nf)
      bfr[nf] = *(const s16x8*)(sb + lq * 1024 + (wn + 16 * nf + col) * 8);
    if (t + 2 < 72) {
      int st = rd + 2; if (st >= 3) st -= 3;
      stage(st, t + 2);
    }
#pragma unroll
    for (int mf = 0; mf < 4; ++mf)
#pragma unroll
      for (int nf = 0; nf < 4; ++nf)
        acc[mf][nf] = __builtin_amdgcn_mfma_f32_16x16x32_bf16(
            af[mf], bfr[nf], acc[mf][nf], 0, 0, 0);
    if (t < 70) {
      __asm__ volatile("s_waitcnt vmcnt(3)" ::: "memory");   // next tile landed
    } else {
      __asm__ volatile("s_waitcnt vmcnt(0)" ::: "memory");
    }
    __builtin_amdgcn_s_barrier();
    rd = (rd + 1 == 3) ? 0 : rd + 1;
  }

  // ---- epilogue: y = relu(acc + bias1) -> per-wave swizzled LDS (bf16) ----
  __hip_bfloat16* yw = (__hip_bfloat16*)smem + wv * 4096;   // 64px x 64n per wave
  int nBase = nb * 128 + wn;
#pragma unroll
  for (int nf = 0; nf < 4; ++nf) {
    float b1v = bias1[nBase + nf * 16 + col];
#pragma unroll
    for (int mf = 0; mf < 4; ++mf) {
      f32x4 a = acc[mf][nf];
#pragma unroll
      for (int r = 0; r < 4; ++r) {
        int pl = mf * 16 + lq * 4 + r;
        int nl = nf * 16 + col;
        float v = a[r] + b1v;
        v = v > 0.f ? v : 0.f;
        int off = (pl * 128 + nl * 2) ^ ((pl & 7) << 4);
        *(unsigned short*)((char*)yw + off) = bfbits(v);
      }
    }
  }

  // ---- capsule 16x16 matmul per group via MFMA (K=16 zero-padded) ----
  int gb = nb * 8 + (wv & 1) * 4;
  s16x8 wf[4];
  f32x4 cinit[4];
#pragma unroll
  for (int g = 0; g < 4; ++g) {
    int gg = gb + g;
    s16x8 bw = {0, 0, 0, 0, 0, 0, 0, 0};
    if (lq < 2) {
#pragma unroll
      for (int j = 0; j < 8; ++j)
        bw[j] = (short)bfbits(capsW[(8 * lq + j) * 512 + gg * 16 + col]);
    }
    wf[g] = bw;
    float cb = capsB[gg * 16 + col];
    cinit[g] = f32x4{cb, cb, cb, cb};
  }
#pragma unroll
  for (int mf = 0; mf < 4; ++mf) {
    int prow = 16 * mf + col;
    f32x4 dd[4];
#pragma unroll
    for (int g = 0; g < 4; ++g) {
      s16x8 afv = {0, 0, 0, 0, 0, 0, 0, 0};
      if (lq < 2) {
        int off = (prow * 128 + g * 32 + lq * 16) ^ ((prow & 7) << 4);
        afv = *(const s16x8*)((char*)yw + off);
      }
      dd[g] = __builtin_amdgcn_mfma_f32_16x16x32_bf16(afv, wf[g], cinit[g], 0, 0, 0);
    }
    long pgl = (long)(p0 + wm) + 16 * mf;
#pragma unroll
    for (int r = 0; r < 4; ++r) {
      long pg = pgl + 4 * lq + r;
      f32x4 o = {dd[0][r], dd[1][r], dd[2][r], dd[3][r]};
      *(f32x4*)(out + (pg * 16 + col) * 32 + gb) = o;
    }
  }
}

// ---------------------------------------------------------------------------
// Fallback (round-1 kernel, needs only 2.4 MB ws) in case ws is small
// ---------------------------------------------------------------------------
__global__ __launch_bounds__(256, 3)
void caps_main_v1(const float* __restrict__ in, const __hip_bfloat16* __restrict__ wt,
                  const float* __restrict__ bias1, const float* __restrict__ capsW,
                  const float* __restrict__ capsB, float* __restrict__ out) {
  __shared__ __align__(16) unsigned char smem[32768];
  __hip_bfloat16* sA = (__hip_bfloat16*)smem;
  __hip_bfloat16* sB = (__hip_bfloat16*)(smem + 8192);

  int bid = (int)blockIdx.x;
  bid = (bid & 7) * 98 + (bid >> 3);
  int mblk = bid >> 2;
  int nb = bid & 3;
  int p0 = mblk * 128;

  int tid = threadIdx.x;
  int lane = tid & 63;
  int wv = tid >> 6;
  int wm = (wv >> 1) * 64;
  int wn = (wv & 1) * 64;
  int col = lane & 15;
  int lq = lane >> 4;

  int am = tid & 127;
  int ah = tid >> 7;
  int p = p0 + am;
  int bb = p / 784;
  int rr = p - bb * 784;
  int ho = rr / 28;
  int wo = rr - ho * 28;

  f32x4 acc[4][4] = {};
  const __hip_bfloat16* wtb = wt + nb * 4096;

  for (int kp = 0; kp < 9; ++kp) {
    int kh = kp / 3;
    int kw = kp - kh * 3;
    int h = 2 * ho + kh, ww = 2 * wo + kw;
    bool valid = (h < 56) && (ww < 56);
    const float* arow = in + (((bb * 56 + h) * 56 + ww) * 256) + ah * 16;
#pragma unroll
    for (int tc = 0; tc < 8; ++tc) {
      int t = kp * 8 + tc;
      __syncthreads();
      const __hip_bfloat16* bsrc = wtb + t * 16384 + tid * 8;
      gll16(sB + (wv * 512), bsrc);
      gll16(sB + 2048 + (wv * 512), bsrc + 2048);
      f32x4 v0, v1, v2, v3;
      if (valid) {
        const f32x4* apv = (const f32x4*)(arow + tc * 32);
        v0 = apv[0]; v1 = apv[1]; v2 = apv[2]; v3 = apv[3];
      } else {
        v0 = f32x4{0.f, 0.f, 0.f, 0.f}; v1 = v0; v2 = v0; v3 = v0;
      }
      u16x8 pk0, pk1;
#pragma unroll
      for (int j = 0; j < 4; ++j) {
        pk0[j] = bfbits(v0[j]); pk0[j + 4] = bfbits(v1[j]);
        pk1[j] = bfbits(v2[j]); pk1[j + 4] = bfbits(v3[j]);
      }
      *(u16x8*)(sA + (ah * 2) * 1024 + am * 8) = pk0;
      *(u16x8*)(sA + (ah * 2 + 1) * 1024 + am * 8) = pk1;
      __syncthreads();
      s16x8 af[4], bfr[4];
#pragma unroll
      for (int mf = 0; mf < 4; ++mf)
        af[mf] = *(const s16x8*)(sA + lq * 1024 + (wm + 16 * mf + col) * 8);
#pragma unroll
      for (int nf = 0; nf < 4; ++nf)
        bfr[nf] = *(const s16x8*)(sB + lq * 1024 + (wn + 16 * nf + col) * 8);
#pragma unroll
      for (int mf = 0; mf < 4; ++mf)
#pragma unroll
        for (int nf = 0; nf < 4; ++nf)
          acc[mf][nf] = __builtin_amdgcn_mfma_f32_16x16x32_bf16(
              af[mf], bfr[nf], acc[mf][nf], 0, 0, 0);
    }
  }

  __syncthreads();

  __hip_bfloat16* yw = (__hip_bfloat16*)smem + wv * 4096;
  int nBase = nb * 128 + wn;
#pragma unroll
  for (int nf = 0; nf < 4; ++nf) {
    float b1v = bias1[nBase + nf * 16 + col];
#pragma unroll
    for (int mf = 0; mf < 4; ++mf) {
      f32x4 a = acc[mf][nf];
#pragma unroll
      for (int r = 0; r < 4; ++r) {
        int pl = mf * 16 + lq * 4 + r;
        int nl = nf * 16 + col;
        float v = a[r] + b1v;
        v = v > 0.f ? v : 0.f;
        int off = (pl * 128 + nl * 2) ^ ((pl & 7) << 4);
        *(unsigned short*)((char*)yw + off) = bfbits(v);
      }
    }
  }

  int gb = nb * 8 + (wv & 1) * 4;
  s16x8 wf[4];
  f32x4 cinit[4];
#pragma unroll
  for (int g = 0; g < 4; ++g) {
    int gg = gb + g;
    s16x8 bw = {0, 0, 0, 0, 0, 0, 0, 0};
    if (lq < 2) {
#pragma unroll
      for (int j = 0; j < 8; ++j)
        bw[j] = (short)bfbits(capsW[(8 * lq + j) * 512 + gg * 16 + col]);
    }
    wf[g] = bw;
    float cb = capsB[gg * 16 + col];
    cinit[g] = f32x4{cb, cb, cb, cb};
  }
#pragma unroll
  for (int mf = 0; mf < 4; ++mf) {
    int prow = 16 * mf + col;
    f32x4 dd[4];
#pragma unroll
    for (int g = 0; g < 4; ++g) {
      s16x8 afv = {0, 0, 0, 0, 0, 0, 0, 0};
      if (lq < 2) {
        int off = (prow * 128 + g * 32 + lq * 16) ^ ((prow & 7) << 4);
        afv = *(const s16x8*)((char*)yw + off);
      }
      dd[g] = __builtin_amdgcn_mfma_f32_16x16x32_bf16(afv, wf[g], cinit[g], 0, 0, 0);
    }
    long pgl = (long)(p0 + wm) + 16 * mf;
#pragma unroll
    for (int r = 0; r < 4; ++r) {
      long pg = pgl + 4 * lq + r;
      f32x4 o = {dd[0][r], dd[1][r], dd[2][r], dd[3][r]};
      *(f32x4*)(out + (pg * 16 + col) * 32 + gb) = o;
    }
  }
}

extern "C" void kernel_launch(void* const* d_in, const int* in_sizes, int n_in,
                              void* d_out, int out_size, void* d_ws, size_t ws_size,
                              hipStream_t stream) {
  const float* inputs = (const float*)d_in[0];
  const float* convW  = (const float*)d_in[1];
  const float* bias1  = (const float*)d_in[2];
  const float* capsW  = (const float*)d_in[3];
  const float* capsB  = (const float*)d_in[4];
  float* out = (float*)d_out;

  __hip_bfloat16* wt = (__hip_bfloat16*)d_ws;                 // 2.36 MB
  const size_t IN_OFF = 2621440;                              // 2.5 MB
  const size_t NEED = IN_OFF + (size_t)27082752 * 2;          // 56.8 MB

  prep_weights<<<576, 256, 0, stream>>>(convW, wt);
  if (ws_size >= NEED) {
    __hip_bfloat16* inp = (__hip_bfloat16*)((char*)d_ws + IN_OFF);
    prep_input_t<<<1824, 256, 0, stream>>>(inputs, inp);
    caps_main_fast<<<392, 512, 0, stream>>>(inp, wt, bias1, capsW, capsB, out);
  } else {
    caps_main_v1<<<784, 256, 0, stream>>>(inputs, wt, bias1, capsW, capsB, out);
  }
}